// Round 17
// baseline (339.046 us; speedup 1.0000x reference)
//
#include <hip/hip_runtime.h>
#include <hip/hip_bf16.h>

#define Nn 50000
#define Ee 1600000
#define Ff 64
#define Rr 5
#define Bb 4
#define Ll 4
#define Kk 2048
#define NBK 196            // dst buckets (dst>>8)
#define SEGB 1280          // segs per bucket = 5 r * 256 dst
#define MsegP (NBK*SEGB)   // 250880 padded segs; s2 = b*1280 + r*256 + dstlo
#define NTC ((Nn+63)/64)   // 782 row tiles of 64 (combm)
#define NCH ((Ee+8191)/8192) // 196 edge chunks
#define WTSL (12*4*64*8)   // 24576 ushorts per layer (swizzled B-frags)

typedef __attribute__((ext_vector_type(8))) short short8;
typedef __attribute__((ext_vector_type(4))) float v4f;
typedef __attribute__((ext_vector_type(4))) unsigned v4u;

// ---- bf16 pack/unpack helpers (storage bf16, math fp32) ----
static __device__ __forceinline__ unsigned short f2b(float f){
  unsigned u = __float_as_uint(f);
  unsigned r = (u + 0x7fffu + ((u>>16)&1u)) >> 16;   // RTN-even
  return (unsigned short)r;
}
static __device__ __forceinline__ unsigned packbf(float lo, float hi){
  return (unsigned)f2b(lo) | ((unsigned)f2b(hi) << 16);
}
static __device__ __forceinline__ float2 unpackbf(unsigned u){
  return make_float2(__uint_as_float(u << 16), __uint_as_float(u & 0xffff0000u));
}

// ---- fused setup A: x2b | inv_init | w1eff | W-swizzle | tflag-zero | misc-zero ----
#define XB_B 6250
#define IV_B (XB_B+196)
#define WE_B (IV_B+128)
#define WS_B (WE_B+48)
#define TF_B (WS_B+4)
#define MS_B (TF_B+1)
__global__ __launch_bounds__(256) void k_setupA(const float* __restrict__ x, unsigned* __restrict__ xb,
    int* __restrict__ inv, const float* __restrict__ w1, float* __restrict__ w1e,
    const float* __restrict__ bases, const float* __restrict__ comps, const float* __restrict__ roots,
    unsigned short* __restrict__ WTs, int* __restrict__ tflag, int* __restrict__ bcnt,
    unsigned* __restrict__ hA, unsigned* __restrict__ hB)
{
  int b = blockIdx.x, t = threadIdx.x;
  if (b < XB_B){
    int idx = b*256 + t;                      // < Nn*32 exactly
    int n = idx >> 5, j = idx & 31;
    float2 v = *(const float2*)&x[(size_t)n*64 + 2*j];
    xb[idx] = packbf(v.x, v.y);
  } else if (b < IV_B){
    int i = (b-XB_B)*256 + t;
    if (i < Nn) inv[i] = -1;
  } else if (b < WE_B){
    int idx = (b-IV_B)*256 + t;               // < 256*128 exactly
    int i = idx >> 7, j = idx & 127;
    w1e[idx] = w1[i*128 + j] + w1[(i+256)*128 + j];
  } else if (b < WS_B){
    int gid = (b-WE_B)*256 + t;               // < 12288 exactly
    int lane = gid & 63, nb = (gid>>6)&3, idx2 = gid>>8;  // idx2 = l*12+kk
    int l = idx2/12, kk = idx2 - l*12;
    int o = nb*16 + (lane & 15);
    int kbase = kk*32 + (lane>>4)*8;
    const float* basesl = bases + (size_t)l*Bb*Ff*Ff;
    const float* compsl = comps + (size_t)l*Rr*Bb;
    const float* rootsl = roots + (size_t)l*Ff*Ff;
    unsigned short* wp = WTs + (size_t)gid*8;
    #pragma unroll
    for (int j=0;j<8;j++){
      int k = kbase + j;
      float s;
      if (k < 320){
        int c = k >> 6, i = k & 63;
        s = 0.f;
        #pragma unroll
        for (int bb2=0;bb2<Bb;bb2++)
          s += compsl[c*Bb+bb2] * basesl[(bb2*Ff + i)*Ff + o];
      } else {
        s = rootsl[(k-320)*Ff + o];
      }
      wp[j] = f2b(s);
    }
  } else if (b < TF_B){
    int i = (b-WS_B)*256 + t;
    if (i < NTC) tflag[i] = 0;
  } else {
    if (t < NBK+1) bcnt[t] = 0;
    if (t < 32){
      xb[(size_t)Nn*32 + t] = 0;              // sentinel rows (zero)
      hA[(size_t)Nn*32 + t] = 0;
      hB[(size_t)Nn*32 + t] = 0;
    }
  }
}

__global__ __launch_bounds__(256) void k_setupB(const int* __restrict__ tidx, int* __restrict__ inv,
                                                int* __restrict__ tflag){
  int k = blockIdx.x*256+threadIdx.x;
  if (k < Kk){
    int n = tidx[k];
    inv[n] = k;
    tflag[n >> 6] = 1;   // benign race; 64-row tiles
  }
}

// ---- CSR build: bucketed counting sort ----
__global__ __launch_bounds__(256) void k_bcnt(const int* __restrict__ ei, int* __restrict__ bcnt){
  __shared__ int h[NBK];
  int t = threadIdx.x;
  for (int i=t;i<NBK;i+=256) h[i]=0;
  __syncthreads();
  int base = blockIdx.x*8192;
  for (int i=0;i<32;i++){
    int e = base + i*256 + t;
    if (e < Ee) atomicAdd(&h[ei[Ee+e]>>8], 1);
  }
  __syncthreads();
  for (int i=t;i<NBK;i+=256) if (h[i]) atomicAdd(&bcnt[i], h[i]);
}

__global__ __launch_bounds__(256) void k_bscan(const int* __restrict__ bcnt, int* __restrict__ bbase,
                                               int* __restrict__ bfill, int* __restrict__ rowptr){
  __shared__ int s[256];
  int t = threadIdx.x;
  int v = (t < NBK) ? bcnt[t] : 0;
  s[t] = v; __syncthreads();
  #pragma unroll
  for (int off=1; off<256; off<<=1){
    int x = (t>=off) ? s[t-off] : 0;
    __syncthreads();
    s[t] += x;
    __syncthreads();
  }
  if (t < NBK){ int ex = s[t]-v; bbase[t]=ex; bfill[t]=ex; }
  if (t == 0){ bbase[NBK] = Ee; rowptr[MsegP] = Ee; }
}

// bin edges into bucket-grouped ebin[]; packed u32 = src | dstlo8<<16 | r<<24
__global__ __launch_bounds__(256) void k_bin(const int* __restrict__ ei, const int* __restrict__ et,
                                             int* __restrict__ bfill, unsigned* __restrict__ ebin){
  __shared__ unsigned led[8192];
  __shared__ int h[NBK], gb[NBK];
  int t = threadIdx.x;
  for (int i=t;i<NBK;i+=256) h[i]=0;
  __syncthreads();
  int base = blockIdx.x*8192;
  for (int i=0;i<32;i++){
    int e = base + i*256 + t;
    if (e < Ee){
      int src = ei[e];
      int dst = ei[Ee+e];
      int r = et[e];
      led[i*256+t] = (unsigned)src | ((unsigned)(dst&255)<<16) | ((unsigned)r<<24);
      atomicAdd(&h[dst>>8], 1);
    }
  }
  __syncthreads();
  for (int i=t;i<NBK;i+=256) if (h[i]){ gb[i] = atomicAdd(&bfill[i], h[i]); h[i] = 0; }
  __syncthreads();
  for (int i=0;i<32;i++){
    int e = base + i*256 + t;
    if (e < Ee){
      int b = ei[Ee+e]>>8;
      int off = atomicAdd(&h[b], 1);
      ebin[gb[b]+off] = led[i*256+t];
    }
  }
}

// per-bucket seg sort: counts -> scan -> rowptr + scatter srcs (bucket-private region)
__global__ __launch_bounds__(512) void k_sort(const unsigned* __restrict__ ebin, const int* __restrict__ bbase,
                                              unsigned short* __restrict__ srcs, int* __restrict__ rowptr){
  __shared__ int cntA[SEGB], excA[SEGB];
  int b = blockIdx.x, t = threadIdx.x;
  int base = bbase[b], cnt = bbase[b+1]-base;
  for (int i=t;i<SEGB;i+=512) cntA[i]=0;
  __syncthreads();
  for (int i=t;i<cnt;i+=512){
    unsigned u = ebin[base+i];
    int segl = (int)((u>>24)&7u)*256 + (int)((u>>16)&255u);
    atomicAdd(&cntA[segl], 1);
  }
  __syncthreads();
  for (int i=t;i<SEGB;i+=512) excA[i]=cntA[i];
  __syncthreads();
  for (int off=1; off<SEGB; off<<=1){
    int i0=t, i1=t+512, i2=t+1024;
    int v0 = (i0>=off)? excA[i0-off] : 0;
    int v1 = (i1>=off)? excA[i1-off] : 0;
    int v2 = (i2<SEGB && i2>=off)? excA[i2-off] : 0;
    __syncthreads();
    excA[i0]+=v0;
    excA[i1]+=v1;
    if (i2<SEGB) excA[i2]+=v2;
    __syncthreads();
  }
  for (int i=t;i<SEGB;i+=512){
    int ex = excA[i]-cntA[i];
    excA[i] = ex;
    rowptr[b*SEGB+i] = base + ex;
    cntA[i] = 0;
  }
  __syncthreads();
  for (int i=t;i<cnt;i+=512){
    unsigned u = ebin[base+i];
    int segl = (int)((u>>24)&7u)*256 + (int)((u>>16)&255u);
    int off = atomicAdd(&cntA[segl], 1);
    srcs[base + excA[segl] + off] = (unsigned short)(u & 0xffffu);
  }
}

// ---- gather pass: 16 edges of one segment via 4 independent dwordx4 loads.
// 8 lanes per edge (li = l2&7, 16 B each), sub = l2>>3 picks edge slot.
static __device__ __forceinline__ void gpass(int mys, float* A, int p, int half5, int sub, int li,
                                             const unsigned* __restrict__ h2)
{
  int s0 = __shfl(mys, half5 + p +      sub, 64);
  int s1 = __shfl(mys, half5 + p +  4 + sub, 64);
  int s2 = __shfl(mys, half5 + p +  8 + sub, 64);
  int s3 = __shfl(mys, half5 + p + 12 + sub, 64);
  uint4 g0 = *(const uint4*)&h2[(size_t)s0*32 + li*4];
  uint4 g1 = *(const uint4*)&h2[(size_t)s1*32 + li*4];
  uint4 g2 = *(const uint4*)&h2[(size_t)s2*32 + li*4];
  uint4 g3 = *(const uint4*)&h2[(size_t)s3*32 + li*4];
  float2 f;
  f=unpackbf(g0.x); A[0]+=f.x; A[1]+=f.y;  f=unpackbf(g0.y); A[2]+=f.x; A[3]+=f.y;
  f=unpackbf(g0.z); A[4]+=f.x; A[5]+=f.y;  f=unpackbf(g0.w); A[6]+=f.x; A[7]+=f.y;
  f=unpackbf(g1.x); A[0]+=f.x; A[1]+=f.y;  f=unpackbf(g1.y); A[2]+=f.x; A[3]+=f.y;
  f=unpackbf(g1.z); A[4]+=f.x; A[5]+=f.y;  f=unpackbf(g1.w); A[6]+=f.x; A[7]+=f.y;
  f=unpackbf(g2.x); A[0]+=f.x; A[1]+=f.y;  f=unpackbf(g2.y); A[2]+=f.x; A[3]+=f.y;
  f=unpackbf(g2.z); A[4]+=f.x; A[5]+=f.y;  f=unpackbf(g2.w); A[6]+=f.x; A[7]+=f.y;
  f=unpackbf(g3.x); A[0]+=f.x; A[1]+=f.y;  f=unpackbf(g3.y); A[2]+=f.x; A[3]+=f.y;
  f=unpackbf(g3.z); A[4]+=f.x; A[5]+=f.y;  f=unpackbf(g3.w); A[6]+=f.x; A[7]+=f.y;
}

static __device__ __forceinline__ void tail_gather(float* A, int s, int e, int li,
    const unsigned short* __restrict__ srcs, const unsigned* __restrict__ h2)
{
  for (int i = s; i < e; i++){
    uint4 g = *(const uint4*)&h2[(size_t)srcs[i]*32 + li*4];
    float2 f;
    f=unpackbf(g.x); A[0]+=f.x; A[1]+=f.y;  f=unpackbf(g.y); A[2]+=f.x; A[3]+=f.y;
    f=unpackbf(g.z); A[4]+=f.x; A[5]+=f.y;  f=unpackbf(g.w); A[6]+=f.x; A[7]+=f.y;
  }
}

static __device__ __forceinline__ void merge_store2(float* aA, float* aB, int wl, int sub, int li,
    int r, int dstA, int degA, int degB, unsigned* __restrict__ y2)
{
  #pragma unroll
  for (int k=0;k<8;k++){
    aA[k] += __shfl(aA[k], wl^8, 64);
    aB[k] += __shfl(aB[k], wl^8, 64);
  }
  #pragma unroll
  for (int k=0;k<8;k++){
    aA[k] += __shfl(aA[k], wl^16, 64);
    aB[k] += __shfl(aB[k], wl^16, 64);
  }
  if (sub == 0){
    if (dstA < Nn){
      float sc = (degA > 0) ? 1.0f/(float)degA : 0.f;
      v4u o;
      o.x = packbf(aA[0]*sc, aA[1]*sc);
      o.y = packbf(aA[2]*sc, aA[3]*sc);
      o.z = packbf(aA[4]*sc, aA[5]*sc);
      o.w = packbf(aA[6]*sc, aA[7]*sc);
      __builtin_nontemporal_store(o, (v4u*)&y2[((size_t)r*Nn + dstA)*32 + li*4]);
    }
    if (dstA + 1 < Nn){
      float sc = (degB > 0) ? 1.0f/(float)degB : 0.f;
      v4u o;
      o.x = packbf(aB[0]*sc, aB[1]*sc);
      o.y = packbf(aB[2]*sc, aB[3]*sc);
      o.z = packbf(aB[4]*sc, aB[5]*sc);
      o.w = packbf(aB[6]*sc, aB[7]*sc);
      __builtin_nontemporal_store(o, (v4u*)&y2[((size_t)r*Nn + dstA + 1)*32 + li*4]);
    }
  }
}

// ---- k_seg: pipelined QUAD — 4 consecutive segments per half-wave.
// Trips: int4 rowptr (1) -> ALL 4 srcs bursts (1) -> pair0 gathers (1) ->
// pair1 gathers (1) = 1.0 trips/segment. Accumulators REUSED across pairs
// (sequential processing) to keep VGPR low (R15's quad died on occupancy).
__global__ __launch_bounds__(256) void k_seg(const unsigned short* __restrict__ srcs,
    const int* __restrict__ rowptr, const unsigned* __restrict__ h2, unsigned* __restrict__ y2)
{
  int tid = threadIdx.x;
  int hw = tid >> 5;
  int l2 = tid & 31, li = l2 & 7, sub = l2 >> 3;
  int half5 = tid & 32;
  int wl = tid & 63;
  int sQ = blockIdx.x*32 + hw*4;            // quad: sQ..sQ+3 (same r, same bucket)
  int b = sQ / SEGB;
  int segl = sQ - b*SEGB;
  int r = segl >> 8;
  int dst0 = b*256 + (segl & 255);
  int4 pp = *(const int4*)&rowptr[sQ];      // sQ%4==0 -> 16B aligned
  int p4 = rowptr[sQ+4];
  int d0 = pp.y-pp.x, d1 = pp.z-pp.y, d2 = pp.w-pp.z, d3 = p4-pp.w;
  // all 4 bursts in one round trip (srcs padded)
  unsigned ld0 = srcs[pp.x + l2];
  unsigned ld1 = srcs[pp.y + l2];
  unsigned ld2 = srcs[pp.z + l2];
  unsigned ld3 = srcs[pp.w + l2];
  float aA[8], aB[8];

  // ---- pair 0 (segments sQ, sQ+1) ----
  {
    int myA = (l2 < d0) ? (int)ld0 : Nn;    // sentinel: zero row
    int myB = (l2 < d1) ? (int)ld1 : Nn;
    #pragma unroll
    for (int k=0;k<8;k++){ aA[k]=0.f; aB[k]=0.f; }
    gpass(myA, aA, 0, half5, sub, li, h2);
    gpass(myB, aB, 0, half5, sub, li, h2);
    if (d0 > 16) gpass(myA, aA, 16, half5, sub, li, h2);
    if (d1 > 16) gpass(myB, aB, 16, half5, sub, li, h2);
    if (sub == 0){
      if (d0 > 32) tail_gather(aA, pp.x+32, pp.y, li, srcs, h2);
      if (d1 > 32) tail_gather(aB, pp.y+32, pp.z, li, srcs, h2);
    }
    merge_store2(aA, aB, wl, sub, li, r, dst0, d0, d1, y2);
  }
  // ---- pair 1 (segments sQ+2, sQ+3) — accumulators reused ----
  {
    int myA = (l2 < d2) ? (int)ld2 : Nn;
    int myB = (l2 < d3) ? (int)ld3 : Nn;
    #pragma unroll
    for (int k=0;k<8;k++){ aA[k]=0.f; aB[k]=0.f; }
    gpass(myA, aA, 0, half5, sub, li, h2);
    gpass(myB, aB, 0, half5, sub, li, h2);
    if (d2 > 16) gpass(myA, aA, 16, half5, sub, li, h2);
    if (d3 > 16) gpass(myB, aB, 16, half5, sub, li, h2);
    if (sub == 0){
      if (d2 > 32) tail_gather(aA, pp.z+32, pp.w, li, srcs, h2);
      if (d3 > 32) tail_gather(aB, pp.w+32, p4,   li, srcs, h2);
    }
    merge_store2(aA, aB, wl, sub, li, r, dst0+2, d2, d3, y2);
  }
}

// layer-3: only target-node segments (5 * 2048), single segment per half-wave
__global__ __launch_bounds__(256) void k_seg_t(const unsigned short* __restrict__ srcs,
    const int* __restrict__ rowptr, const unsigned* __restrict__ h2, unsigned* __restrict__ y2,
    const int* __restrict__ tidx)
{
  int idx = blockIdx.x*8 + (threadIdx.x >> 5);
  if (idx >= Rr*Kk) return;
  int r = idx >> 11;           // Kk == 2048
  int k = idx & (Kk-1);
  int dst = tidx[k];
  int s2 = (dst>>8)*SEGB + r*256 + (dst&255);
  int tid = threadIdx.x;
  int l2 = tid & 31, li = l2 & 7, sub = l2 >> 3;
  int half5 = tid & 32;
  int wl = tid & 63;
  int s = rowptr[s2], e = rowptr[s2+1];
  int deg = e - s;
  unsigned ld = srcs[s + l2];
  int mys = (l2 < deg) ? (int)ld : Nn;
  float a[8] = {0.f,0.f,0.f,0.f,0.f,0.f,0.f,0.f};
  gpass(mys, a, 0, half5, sub, li, h2);
  if (deg > 16) gpass(mys, a, 16, half5, sub, li, h2);
  if (deg > 32 && sub == 0) tail_gather(a, s+32, e, li, srcs, h2);
  #pragma unroll
  for (int q=0;q<8;q++) a[q] += __shfl(a[q], wl^8, 64);
  #pragma unroll
  for (int q=0;q<8;q++) a[q] += __shfl(a[q], wl^16, 64);
  if (sub == 0){
    float sc = (deg > 0) ? 1.0f/(float)deg : 0.f;
    v4u o;
    o.x = packbf(a[0]*sc, a[1]*sc);
    o.y = packbf(a[2]*sc, a[3]*sc);
    o.z = packbf(a[4]*sc, a[5]*sc);
    o.w = packbf(a[6]*sc, a[7]*sc);
    __builtin_nontemporal_store(o, (v4u*)&y2[((size_t)r*Nn + dst)*32 + li*4]);
  }
}

// MFMA combine, LDS-free: [N,384]@[384,64]. Block = 256 thr (4 waves) x 64 rows.
// y2 A-frags via NT loads (read-once; keep h resident in L2).
__global__ __launch_bounds__(256) void k_combm(const unsigned* __restrict__ y2, const unsigned* __restrict__ h2,
    const unsigned short* __restrict__ WTsl, const float* __restrict__ bias,
    unsigned short* __restrict__ hn, const int* __restrict__ inv, float* __restrict__ sel,
    int layer, const int* __restrict__ tflag)
{
  if (layer == Ll-1 && tflag[blockIdx.x] == 0) return;
  int wv = threadIdx.x >> 6, lane = threadIdx.x & 63;
  int m = lane & 15, q = lane >> 4;
  int row = blockIdx.x*64 + wv*16 + m;
  int rowc = (row < Nn) ? row : Nn-1;      // clamp loads
  const char* y2c = (const char*)y2;
  const char* h2c = (const char*)h2;
  const unsigned short* wl = WTsl + (size_t)lane*8;

  v4f acc0 = {0.f,0.f,0.f,0.f}, acc1 = {0.f,0.f,0.f,0.f},
      acc2 = {0.f,0.f,0.f,0.f}, acc3 = {0.f,0.f,0.f,0.f};

  #pragma unroll
  for (int kk=0; kk<12; kk++){
    short8 a;
    if (kk < 10)
      a = __builtin_nontemporal_load((const short8*)(y2c + ((size_t)((kk>>1)*Nn + rowc))*128 + (size_t)(kk&1)*64 + q*16));
    else
      a = *(const short8*)(h2c + ((size_t)rowc)*128 + (size_t)(kk&1)*64 + q*16);
    const unsigned short* wb = wl + kk*2048;
    short8 b0 = *(const short8*)(wb);
    short8 b1 = *(const short8*)(wb + 512);
    short8 b2 = *(const short8*)(wb + 1024);
    short8 b3 = *(const short8*)(wb + 1536);
    acc0 = __builtin_amdgcn_mfma_f32_16x16x32_bf16(a, b0, acc0, 0, 0, 0);
    acc1 = __builtin_amdgcn_mfma_f32_16x16x32_bf16(a, b1, acc1, 0, 0, 0);
    acc2 = __builtin_amdgcn_mfma_f32_16x16x32_bf16(a, b2, acc2, 0, 0, 0);
    acc3 = __builtin_amdgcn_mfma_f32_16x16x32_bf16(a, b3, acc3, 0, 0, 0);
  }

  float bc0 = bias[ 0 + m], bc1 = bias[16 + m], bc2 = bias[32 + m], bc3 = bias[48 + m];
  #pragma unroll
  for (int j=0;j<4;j++){
    int node = blockIdx.x*64 + wv*16 + q*4 + j;
    if (node < Nn){
      float r0 = tanhf(acc0[j] + bc0);
      float r1 = tanhf(acc1[j] + bc1);
      float r2 = tanhf(acc2[j] + bc2);
      float r3 = tanhf(acc3[j] + bc3);
      if (layer != Ll-1){
        unsigned short* hp = &hn[(size_t)node*64];
        hp[ 0 + m] = f2b(r0);
        hp[16 + m] = f2b(r1);
        hp[32 + m] = f2b(r2);
        hp[48 + m] = f2b(r3);
      }
      int k = inv[node];
      if (k >= 0){
        float* sp = &sel[(size_t)k*256 + layer*64];
        sp[ 0 + m] = r0;
        sp[16 + m] = r1;
        sp[32 + m] = r2;
        sp[48 + m] = r3;
      }
    }
  }
}

__global__ __launch_bounds__(128) void k_mlp(const float* __restrict__ sel, const float* __restrict__ w1e,
    const float* __restrict__ b1, const float* __restrict__ w2, const float* __restrict__ b2,
    float* __restrict__ out)
{
  __shared__ float sfeat[256];
  __shared__ float partial[2];
  int k = blockIdx.x, j = threadIdx.x;
  for (int idx=j; idx<256; idx+=128) sfeat[idx] = sel[(size_t)k*256 + idx];
  __syncthreads();
  float a = b1[j];
  for (int i=0;i<256;i++) a += sfeat[i] * w1e[i*128 + j];
  a = fmaxf(a, 0.f);
  float v = a * w2[j];
  #pragma unroll
  for (int off=32; off>0; off>>=1) v += __shfl_down(v, off, 64);
  if ((j & 63) == 0) partial[j>>6] = v;
  __syncthreads();
  if (j == 0) out[k] = partial[0] + partial[1] + b2[0];
}

extern "C" void kernel_launch(void* const* d_in, const int* in_sizes, int n_in,
                              void* d_out, int out_size, void* d_ws, size_t ws_size,
                              hipStream_t stream){
  const float* x     = (const float*)d_in[0];
  const int*  ei     = (const int*)d_in[1];
  const int*  et     = (const int*)d_in[2];
  const int*  tidx   = (const int*)d_in[3];
  const float* bases = (const float*)d_in[4];
  const float* comps = (const float*)d_in[5];
  const float* roots = (const float*)d_in[6];
  const float* biases= (const float*)d_in[7];
  const float* w1    = (const float*)d_in[8];
  const float* b1    = (const float*)d_in[9];
  const float* w2    = (const float*)d_in[10];
  const float* b2    = (const float*)d_in[11];
  float* out = (float*)d_out;

  char* wsp = (char*)d_ws;
  size_t off = 0;
  auto alloc = [&](size_t bytes)->void*{ void* p = wsp + off; off += (bytes + 255) & ~size_t(255); return p; };
  unsigned* xb    = (unsigned*)alloc(sizeof(unsigned)*((size_t)Nn+1)*32);  // +sentinel row
  unsigned* hA    = (unsigned*)alloc(sizeof(unsigned)*((size_t)Nn+1)*32);
  unsigned* hB    = (unsigned*)alloc(sizeof(unsigned)*((size_t)Nn+1)*32);
  unsigned* y2    = (unsigned*)alloc(sizeof(unsigned)*(size_t)Rr*Nn*32);   // 32 MB
  unsigned* ebin  = (unsigned*)alloc(sizeof(unsigned)*(size_t)Ee);         // 6.4 MB
  int*      bcnt  = (int*)  alloc(sizeof(int)*(NBK+1));
  int*      bbase = (int*)  alloc(sizeof(int)*(NBK+1));
  int*      bfill = (int*)  alloc(sizeof(int)*(NBK));
  int*      rowptr= (int*)  alloc(sizeof(int)*(MsegP+1));                  // 1 MB
  unsigned short* srcs = (unsigned short*)alloc(sizeof(unsigned short)*((size_t)Ee+64)); // padded
  unsigned short* WTs  = (unsigned short*)alloc(sizeof(unsigned short)*(size_t)Ll*WTSL);
  float*    sel   = (float*)alloc(sizeof(float)*(size_t)Kk*256);           // 2 MB
  float*    w1e   = (float*)alloc(sizeof(float)*256*128);
  int*      inv   = (int*)  alloc(sizeof(int)*(size_t)Nn);
  int*      tflag = (int*)  alloc(sizeof(int)*NTC);
  (void)ws_size;

  k_setupA<<<MS_B+1, 256, 0, stream>>>(x, xb, inv, w1, w1e, bases, comps, roots,
                                       WTs, tflag, bcnt, hA, hB);
  k_setupB<<<(Kk+255)/256, 256, 0, stream>>>(tidx, inv, tflag);
  k_bcnt<<<NCH, 256, 0, stream>>>(ei, bcnt);
  k_bscan<<<1, 256, 0, stream>>>(bcnt, bbase, bfill, rowptr);
  k_bin<<<NCH, 256, 0, stream>>>(ei, et, bfill, ebin);
  k_sort<<<NBK, 512, 0, stream>>>(ebin, bbase, srcs, rowptr);

  const unsigned* hc = xb;
  unsigned* hn = hA;
  for (int l=0;l<Ll;l++){
    if (l < Ll-1)
      k_seg<<<MsegP/32, 256, 0, stream>>>(srcs, rowptr, hc, y2);
    else
      k_seg_t<<<(Rr*Kk+7)/8, 256, 0, stream>>>(srcs, rowptr, hc, y2, tidx);
    k_combm<<<NTC, 256, 0, stream>>>(y2, hc, WTs + (size_t)l*WTSL, biases + (size_t)l*Ff,
                                     (unsigned short*)hn, inv, sel, l, tflag);
    hc = hn;
    hn = (hn == hA) ? hB : hA;
  }
  k_mlp<<<Kk, 128, 0, stream>>>(sel, w1e, b1, w2, b2, out);
}

// Round 18
// 327.793 us; speedup vs baseline: 1.0343x; 1.0343x over previous
//
#include <hip/hip_runtime.h>
#include <hip/hip_bf16.h>

#define Nn 50000
#define Ee 1600000
#define Ff 64
#define Rr 5
#define Bb 4
#define Ll 4
#define Kk 2048
#define NBK 196            // dst buckets (dst>>8)
#define SEGB 1280          // segs per bucket = 5 r * 256 dst
#define MsegP (NBK*SEGB)   // 250880 padded segs; s2 = b*1280 + r*256 + dstlo
#define NTC ((Nn+63)/64)   // 782 row tiles of 64 (combm)
#define NCH ((Ee+8191)/8192) // 196 edge chunks
#define WTSL (12*4*64*8)   // 24576 ushorts per layer (swizzled B-frags)

typedef __attribute__((ext_vector_type(8))) short short8;
typedef __attribute__((ext_vector_type(4))) float v4f;

// ---- bf16 pack/unpack helpers (storage bf16, math fp32) ----
static __device__ __forceinline__ unsigned short f2b(float f){
  unsigned u = __float_as_uint(f);
  unsigned r = (u + 0x7fffu + ((u>>16)&1u)) >> 16;   // RTN-even
  return (unsigned short)r;
}
static __device__ __forceinline__ unsigned packbf(float lo, float hi){
  return (unsigned)f2b(lo) | ((unsigned)f2b(hi) << 16);
}
static __device__ __forceinline__ float2 unpackbf(unsigned u){
  return make_float2(__uint_as_float(u << 16), __uint_as_float(u & 0xffff0000u));
}

// ---- fused setup A: x2b | inv_init | w1eff | W-swizzle | tflag-zero | misc-zero ----
#define XB_B 6250
#define IV_B (XB_B+196)
#define WE_B (IV_B+128)
#define WS_B (WE_B+48)
#define TF_B (WS_B+4)
#define MS_B (TF_B+1)
__global__ __launch_bounds__(256) void k_setupA(const float* __restrict__ x, unsigned* __restrict__ xb,
    int* __restrict__ inv, const float* __restrict__ w1, float* __restrict__ w1e,
    const float* __restrict__ bases, const float* __restrict__ comps, const float* __restrict__ roots,
    unsigned short* __restrict__ WTs, int* __restrict__ tflag, int* __restrict__ bcnt,
    unsigned* __restrict__ hA, unsigned* __restrict__ hB)
{
  int b = blockIdx.x, t = threadIdx.x;
  if (b < XB_B){
    int idx = b*256 + t;                      // < Nn*32 exactly
    int n = idx >> 5, j = idx & 31;
    float2 v = *(const float2*)&x[(size_t)n*64 + 2*j];
    xb[idx] = packbf(v.x, v.y);
  } else if (b < IV_B){
    int i = (b-XB_B)*256 + t;
    if (i < Nn) inv[i] = -1;
  } else if (b < WE_B){
    int idx = (b-IV_B)*256 + t;               // < 256*128 exactly
    int i = idx >> 7, j = idx & 127;
    w1e[idx] = w1[i*128 + j] + w1[(i+256)*128 + j];
  } else if (b < WS_B){
    int gid = (b-WE_B)*256 + t;               // < 12288 exactly
    int lane = gid & 63, nb = (gid>>6)&3, idx2 = gid>>8;  // idx2 = l*12+kk
    int l = idx2/12, kk = idx2 - l*12;
    int o = nb*16 + (lane & 15);
    int kbase = kk*32 + (lane>>4)*8;
    const float* basesl = bases + (size_t)l*Bb*Ff*Ff;
    const float* compsl = comps + (size_t)l*Rr*Bb;
    const float* rootsl = roots + (size_t)l*Ff*Ff;
    unsigned short* wp = WTs + (size_t)gid*8;
    #pragma unroll
    for (int j=0;j<8;j++){
      int k = kbase + j;
      float s;
      if (k < 320){
        int c = k >> 6, i = k & 63;
        s = 0.f;
        #pragma unroll
        for (int bb2=0;bb2<Bb;bb2++)
          s += compsl[c*Bb+bb2] * basesl[(bb2*Ff + i)*Ff + o];
      } else {
        s = rootsl[(k-320)*Ff + o];
      }
      wp[j] = f2b(s);
    }
  } else if (b < TF_B){
    int i = (b-WS_B)*256 + t;
    if (i < NTC) tflag[i] = 0;
  } else {
    if (t < NBK+1) bcnt[t] = 0;
    if (t < 32){
      xb[(size_t)Nn*32 + t] = 0;              // sentinel rows (zero)
      hA[(size_t)Nn*32 + t] = 0;
      hB[(size_t)Nn*32 + t] = 0;
    }
  }
}

__global__ __launch_bounds__(256) void k_setupB(const int* __restrict__ tidx, int* __restrict__ inv,
                                                int* __restrict__ tflag){
  int k = blockIdx.x*256+threadIdx.x;
  if (k < Kk){
    int n = tidx[k];
    inv[n] = k;
    tflag[n >> 6] = 1;   // benign race; 64-row tiles
  }
}

// ---- CSR build: bucketed counting sort ----
__global__ __launch_bounds__(256) void k_bcnt(const int* __restrict__ ei, int* __restrict__ bcnt){
  __shared__ int h[NBK];
  int t = threadIdx.x;
  for (int i=t;i<NBK;i+=256) h[i]=0;
  __syncthreads();
  int base = blockIdx.x*8192;
  for (int i=0;i<32;i++){
    int e = base + i*256 + t;
    if (e < Ee) atomicAdd(&h[ei[Ee+e]>>8], 1);
  }
  __syncthreads();
  for (int i=t;i<NBK;i+=256) if (h[i]) atomicAdd(&bcnt[i], h[i]);
}

__global__ __launch_bounds__(256) void k_bscan(const int* __restrict__ bcnt, int* __restrict__ bbase,
                                               int* __restrict__ bfill, int* __restrict__ rowptr){
  __shared__ int s[256];
  int t = threadIdx.x;
  int v = (t < NBK) ? bcnt[t] : 0;
  s[t] = v; __syncthreads();
  #pragma unroll
  for (int off=1; off<256; off<<=1){
    int x = (t>=off) ? s[t-off] : 0;
    __syncthreads();
    s[t] += x;
    __syncthreads();
  }
  if (t < NBK){ int ex = s[t]-v; bbase[t]=ex; bfill[t]=ex; }
  if (t == 0){ bbase[NBK] = Ee; rowptr[MsegP] = Ee; }
}

// bin edges into bucket-grouped ebin[]; packed u32 = src | dstlo8<<16 | r<<24
__global__ __launch_bounds__(256) void k_bin(const int* __restrict__ ei, const int* __restrict__ et,
                                             int* __restrict__ bfill, unsigned* __restrict__ ebin){
  __shared__ unsigned led[8192];
  __shared__ int h[NBK], gb[NBK];
  int t = threadIdx.x;
  for (int i=t;i<NBK;i+=256) h[i]=0;
  __syncthreads();
  int base = blockIdx.x*8192;
  for (int i=0;i<32;i++){
    int e = base + i*256 + t;
    if (e < Ee){
      int src = ei[e];
      int dst = ei[Ee+e];
      int r = et[e];
      led[i*256+t] = (unsigned)src | ((unsigned)(dst&255)<<16) | ((unsigned)r<<24);
      atomicAdd(&h[dst>>8], 1);
    }
  }
  __syncthreads();
  for (int i=t;i<NBK;i+=256) if (h[i]){ gb[i] = atomicAdd(&bfill[i], h[i]); h[i] = 0; }
  __syncthreads();
  for (int i=0;i<32;i++){
    int e = base + i*256 + t;
    if (e < Ee){
      int b = ei[Ee+e]>>8;
      int off = atomicAdd(&h[b], 1);
      ebin[gb[b]+off] = led[i*256+t];
    }
  }
}

// per-bucket seg sort: counts -> scan -> rowptr + scatter srcs (bucket-private region)
__global__ __launch_bounds__(512) void k_sort(const unsigned* __restrict__ ebin, const int* __restrict__ bbase,
                                              unsigned short* __restrict__ srcs, int* __restrict__ rowptr){
  __shared__ int cntA[SEGB], excA[SEGB];
  int b = blockIdx.x, t = threadIdx.x;
  int base = bbase[b], cnt = bbase[b+1]-base;
  for (int i=t;i<SEGB;i+=512) cntA[i]=0;
  __syncthreads();
  for (int i=t;i<cnt;i+=512){
    unsigned u = ebin[base+i];
    int segl = (int)((u>>24)&7u)*256 + (int)((u>>16)&255u);
    atomicAdd(&cntA[segl], 1);
  }
  __syncthreads();
  for (int i=t;i<SEGB;i+=512) excA[i]=cntA[i];
  __syncthreads();
  for (int off=1; off<SEGB; off<<=1){
    int i0=t, i1=t+512, i2=t+1024;
    int v0 = (i0>=off)? excA[i0-off] : 0;
    int v1 = (i1>=off)? excA[i1-off] : 0;
    int v2 = (i2<SEGB && i2>=off)? excA[i2-off] : 0;
    __syncthreads();
    excA[i0]+=v0;
    excA[i1]+=v1;
    if (i2<SEGB) excA[i2]+=v2;
    __syncthreads();
  }
  for (int i=t;i<SEGB;i+=512){
    int ex = excA[i]-cntA[i];
    excA[i] = ex;
    rowptr[b*SEGB+i] = base + ex;
    cntA[i] = 0;
  }
  __syncthreads();
  for (int i=t;i<cnt;i+=512){
    unsigned u = ebin[base+i];
    int segl = (int)((u>>24)&7u)*256 + (int)((u>>16)&255u);
    int off = atomicAdd(&cntA[segl], 1);
    srcs[base + excA[segl] + off] = (unsigned short)(u & 0xffffu);
  }
}

// ---- gather pass: 16 edges of one segment via 4 independent dwordx4 loads.
// 8 lanes per edge (li = l2&7, 16 B each), sub = l2>>3 picks edge slot.
static __device__ __forceinline__ void gpass(int mys, float* A, int p, int half5, int sub, int li,
                                             const unsigned* __restrict__ h2)
{
  int s0 = __shfl(mys, half5 + p +      sub, 64);
  int s1 = __shfl(mys, half5 + p +  4 + sub, 64);
  int s2 = __shfl(mys, half5 + p +  8 + sub, 64);
  int s3 = __shfl(mys, half5 + p + 12 + sub, 64);
  uint4 g0 = *(const uint4*)&h2[(size_t)s0*32 + li*4];
  uint4 g1 = *(const uint4*)&h2[(size_t)s1*32 + li*4];
  uint4 g2 = *(const uint4*)&h2[(size_t)s2*32 + li*4];
  uint4 g3 = *(const uint4*)&h2[(size_t)s3*32 + li*4];
  float2 f;
  f=unpackbf(g0.x); A[0]+=f.x; A[1]+=f.y;  f=unpackbf(g0.y); A[2]+=f.x; A[3]+=f.y;
  f=unpackbf(g0.z); A[4]+=f.x; A[5]+=f.y;  f=unpackbf(g0.w); A[6]+=f.x; A[7]+=f.y;
  f=unpackbf(g1.x); A[0]+=f.x; A[1]+=f.y;  f=unpackbf(g1.y); A[2]+=f.x; A[3]+=f.y;
  f=unpackbf(g1.z); A[4]+=f.x; A[5]+=f.y;  f=unpackbf(g1.w); A[6]+=f.x; A[7]+=f.y;
  f=unpackbf(g2.x); A[0]+=f.x; A[1]+=f.y;  f=unpackbf(g2.y); A[2]+=f.x; A[3]+=f.y;
  f=unpackbf(g2.z); A[4]+=f.x; A[5]+=f.y;  f=unpackbf(g2.w); A[6]+=f.x; A[7]+=f.y;
  f=unpackbf(g3.x); A[0]+=f.x; A[1]+=f.y;  f=unpackbf(g3.y); A[2]+=f.x; A[3]+=f.y;
  f=unpackbf(g3.z); A[4]+=f.x; A[5]+=f.y;  f=unpackbf(g3.w); A[6]+=f.x; A[7]+=f.y;
}

static __device__ __forceinline__ void tail_gather(float* A, int s, int e, int li,
    const unsigned short* __restrict__ srcs, const unsigned* __restrict__ h2)
{
  for (int i = s; i < e; i++){
    uint4 g = *(const uint4*)&h2[(size_t)srcs[i]*32 + li*4];
    float2 f;
    f=unpackbf(g.x); A[0]+=f.x; A[1]+=f.y;  f=unpackbf(g.y); A[2]+=f.x; A[3]+=f.y;
    f=unpackbf(g.z); A[4]+=f.x; A[5]+=f.y;  f=unpackbf(g.w); A[6]+=f.x; A[7]+=f.y;
  }
}

// ---- k_seg: TWO consecutive segments per half-wave, dwordx4 gathers (best: R14).
// Chain: int2 rowptr -> two srcs bursts -> 8 independent dwordx4 gathers (32 edges).
__global__ __launch_bounds__(256) void k_seg(const unsigned short* __restrict__ srcs,
    const int* __restrict__ rowptr, const unsigned* __restrict__ h2, unsigned* __restrict__ y2)
{
  int tid = threadIdx.x;
  int hw = tid >> 5;
  int l2 = tid & 31, li = l2 & 7, sub = l2 >> 3;
  int half5 = tid & 32;
  int wl = tid & 63;
  int sA = blockIdx.x*16 + hw*2;            // pair: sA, sA+1 (same r, same bucket)
  int b = sA / SEGB;
  int segl = sA - b*SEGB;
  int r = segl >> 8;
  int dstA = b*256 + (segl & 255);
  int2 pp = *(const int2*)&rowptr[sA];      // sA even -> 8B aligned
  int p2 = rowptr[sA+2];
  int degA = pp.y - pp.x, degB = p2 - pp.y;
  unsigned ldA = srcs[pp.x + l2];           // bursts (srcs padded)
  unsigned ldB = srcs[pp.y + l2];
  int mysA = (l2 < degA) ? (int)ldA : Nn;   // sentinel: zero row
  int mysB = (l2 < degB) ? (int)ldB : Nn;
  float aA[8] = {0.f,0.f,0.f,0.f,0.f,0.f,0.f,0.f};
  float aB[8] = {0.f,0.f,0.f,0.f,0.f,0.f,0.f,0.f};

  gpass(mysA, aA, 0, half5, sub, li, h2);
  gpass(mysB, aB, 0, half5, sub, li, h2);
  if (degA > 16) gpass(mysA, aA, 16, half5, sub, li, h2);
  if (degB > 16) gpass(mysB, aB, 16, half5, sub, li, h2);

  // ultra-rare tails (deg > 32): sub0 lanes
  if (sub == 0){
    if (degA > 32) tail_gather(aA, pp.x+32, pp.y, li, srcs, h2);
    if (degB > 32) tail_gather(aB, pp.y+32, p2,   li, srcs, h2);
  }
  // merge subs: xor 8, then xor 16 (within the 32-lane half)
  #pragma unroll
  for (int k=0;k<8;k++){
    aA[k] += __shfl(aA[k], wl^8, 64);
    aB[k] += __shfl(aB[k], wl^8, 64);
  }
  #pragma unroll
  for (int k=0;k<8;k++){
    aA[k] += __shfl(aA[k], wl^16, 64);
    aB[k] += __shfl(aB[k], wl^16, 64);
  }
  if (sub == 0){
    if (dstA < Nn){
      float sc = (degA > 0) ? 1.0f/(float)degA : 0.f;
      uint4 o;
      o.x = packbf(aA[0]*sc, aA[1]*sc);
      o.y = packbf(aA[2]*sc, aA[3]*sc);
      o.z = packbf(aA[4]*sc, aA[5]*sc);
      o.w = packbf(aA[6]*sc, aA[7]*sc);
      *(uint4*)&y2[((size_t)r*Nn + dstA)*32 + li*4] = o;
    }
    if (dstA + 1 < Nn){
      float sc = (degB > 0) ? 1.0f/(float)degB : 0.f;
      uint4 o;
      o.x = packbf(aB[0]*sc, aB[1]*sc);
      o.y = packbf(aB[2]*sc, aB[3]*sc);
      o.z = packbf(aB[4]*sc, aB[5]*sc);
      o.w = packbf(aB[6]*sc, aB[7]*sc);
      *(uint4*)&y2[((size_t)r*Nn + dstA + 1)*32 + li*4] = o;
    }
  }
}

// layer-3: only target-node segments (5 * 2048), single segment per half-wave
__global__ __launch_bounds__(256) void k_seg_t(const unsigned short* __restrict__ srcs,
    const int* __restrict__ rowptr, const unsigned* __restrict__ h2, unsigned* __restrict__ y2,
    const int* __restrict__ tidx)
{
  int idx = blockIdx.x*8 + (threadIdx.x >> 5);
  if (idx >= Rr*Kk) return;
  int r = idx >> 11;           // Kk == 2048
  int k = idx & (Kk-1);
  int dst = tidx[k];
  int s2 = (dst>>8)*SEGB + r*256 + (dst&255);
  int tid = threadIdx.x;
  int l2 = tid & 31, li = l2 & 7, sub = l2 >> 3;
  int half5 = tid & 32;
  int wl = tid & 63;
  int s = rowptr[s2], e = rowptr[s2+1];
  int deg = e - s;
  unsigned ld = srcs[s + l2];
  int mys = (l2 < deg) ? (int)ld : Nn;
  float a[8] = {0.f,0.f,0.f,0.f,0.f,0.f,0.f,0.f};
  gpass(mys, a, 0, half5, sub, li, h2);
  if (deg > 16) gpass(mys, a, 16, half5, sub, li, h2);
  if (deg > 32 && sub == 0) tail_gather(a, s+32, e, li, srcs, h2);
  #pragma unroll
  for (int q=0;q<8;q++) a[q] += __shfl(a[q], wl^8, 64);
  #pragma unroll
  for (int q=0;q<8;q++) a[q] += __shfl(a[q], wl^16, 64);
  if (sub == 0){
    float sc = (deg > 0) ? 1.0f/(float)deg : 0.f;
    uint4 o;
    o.x = packbf(a[0]*sc, a[1]*sc);
    o.y = packbf(a[2]*sc, a[3]*sc);
    o.z = packbf(a[4]*sc, a[5]*sc);
    o.w = packbf(a[6]*sc, a[7]*sc);
    *(uint4*)&y2[((size_t)r*Nn + dst)*32 + li*4] = o;
  }
}

// MFMA combine, LDS-free: [N,384]@[384,64]. Block = 256 thr (4 waves) x 64 rows.
__global__ __launch_bounds__(256) void k_combm(const unsigned* __restrict__ y2, const unsigned* __restrict__ h2,
    const unsigned short* __restrict__ WTsl, const float* __restrict__ bias,
    unsigned short* __restrict__ hn, const int* __restrict__ inv, float* __restrict__ sel,
    int layer, const int* __restrict__ tflag)
{
  if (layer == Ll-1 && tflag[blockIdx.x] == 0) return;
  int wv = threadIdx.x >> 6, lane = threadIdx.x & 63;
  int m = lane & 15, q = lane >> 4;
  int row = blockIdx.x*64 + wv*16 + m;
  int rowc = (row < Nn) ? row : Nn-1;      // clamp loads
  const char* y2c = (const char*)y2;
  const char* h2c = (const char*)h2;
  const unsigned short* wl = WTsl + (size_t)lane*8;

  v4f acc0 = {0.f,0.f,0.f,0.f}, acc1 = {0.f,0.f,0.f,0.f},
      acc2 = {0.f,0.f,0.f,0.f}, acc3 = {0.f,0.f,0.f,0.f};

  #pragma unroll
  for (int kk=0; kk<12; kk++){
    const char* base = (kk < 10)
      ? y2c + ((size_t)((kk>>1)*Nn + rowc))*128 + (size_t)(kk&1)*64
      : h2c + ((size_t)rowc)*128 + (size_t)(kk&1)*64;
    short8 a = *(const short8*)(base + q*16);
    const unsigned short* wb = wl + kk*2048;
    short8 b0 = *(const short8*)(wb);
    short8 b1 = *(const short8*)(wb + 512);
    short8 b2 = *(const short8*)(wb + 1024);
    short8 b3 = *(const short8*)(wb + 1536);
    acc0 = __builtin_amdgcn_mfma_f32_16x16x32_bf16(a, b0, acc0, 0, 0, 0);
    acc1 = __builtin_amdgcn_mfma_f32_16x16x32_bf16(a, b1, acc1, 0, 0, 0);
    acc2 = __builtin_amdgcn_mfma_f32_16x16x32_bf16(a, b2, acc2, 0, 0, 0);
    acc3 = __builtin_amdgcn_mfma_f32_16x16x32_bf16(a, b3, acc3, 0, 0, 0);
  }

  float bc0 = bias[ 0 + m], bc1 = bias[16 + m], bc2 = bias[32 + m], bc3 = bias[48 + m];
  #pragma unroll
  for (int j=0;j<4;j++){
    int node = blockIdx.x*64 + wv*16 + q*4 + j;
    if (node < Nn){
      float r0 = tanhf(acc0[j] + bc0);
      float r1 = tanhf(acc1[j] + bc1);
      float r2 = tanhf(acc2[j] + bc2);
      float r3 = tanhf(acc3[j] + bc3);
      if (layer != Ll-1){
        unsigned short* hp = &hn[(size_t)node*64];
        hp[ 0 + m] = f2b(r0);
        hp[16 + m] = f2b(r1);
        hp[32 + m] = f2b(r2);
        hp[48 + m] = f2b(r3);
      }
      int k = inv[node];
      if (k >= 0){
        float* sp = &sel[(size_t)k*256 + layer*64];
        sp[ 0 + m] = r0;
        sp[16 + m] = r1;
        sp[32 + m] = r2;
        sp[48 + m] = r3;
      }
    }
  }
}

__global__ __launch_bounds__(128) void k_mlp(const float* __restrict__ sel, const float* __restrict__ w1e,
    const float* __restrict__ b1, const float* __restrict__ w2, const float* __restrict__ b2,
    float* __restrict__ out)
{
  __shared__ float sfeat[256];
  __shared__ float partial[2];
  int k = blockIdx.x, j = threadIdx.x;
  for (int idx=j; idx<256; idx+=128) sfeat[idx] = sel[(size_t)k*256 + idx];
  __syncthreads();
  float a = b1[j];
  for (int i=0;i<256;i++) a += sfeat[i] * w1e[i*128 + j];
  a = fmaxf(a, 0.f);
  float v = a * w2[j];
  #pragma unroll
  for (int off=32; off>0; off>>=1) v += __shfl_down(v, off, 64);
  if ((j & 63) == 0) partial[j>>6] = v;
  __syncthreads();
  if (j == 0) out[k] = partial[0] + partial[1] + b2[0];
}

extern "C" void kernel_launch(void* const* d_in, const int* in_sizes, int n_in,
                              void* d_out, int out_size, void* d_ws, size_t ws_size,
                              hipStream_t stream){
  const float* x     = (const float*)d_in[0];
  const int*  ei     = (const int*)d_in[1];
  const int*  et     = (const int*)d_in[2];
  const int*  tidx   = (const int*)d_in[3];
  const float* bases = (const float*)d_in[4];
  const float* comps = (const float*)d_in[5];
  const float* roots = (const float*)d_in[6];
  const float* biases= (const float*)d_in[7];
  const float* w1    = (const float*)d_in[8];
  const float* b1    = (const float*)d_in[9];
  const float* w2    = (const float*)d_in[10];
  const float* b2    = (const float*)d_in[11];
  float* out = (float*)d_out;

  char* wsp = (char*)d_ws;
  size_t off = 0;
  auto alloc = [&](size_t bytes)->void*{ void* p = wsp + off; off += (bytes + 255) & ~size_t(255); return p; };
  unsigned* xb    = (unsigned*)alloc(sizeof(unsigned)*((size_t)Nn+1)*32);  // +sentinel row
  unsigned* hA    = (unsigned*)alloc(sizeof(unsigned)*((size_t)Nn+1)*32);
  unsigned* hB    = (unsigned*)alloc(sizeof(unsigned)*((size_t)Nn+1)*32);
  unsigned* y2    = (unsigned*)alloc(sizeof(unsigned)*(size_t)Rr*Nn*32);   // 32 MB
  unsigned* ebin  = (unsigned*)alloc(sizeof(unsigned)*(size_t)Ee);         // 6.4 MB
  int*      bcnt  = (int*)  alloc(sizeof(int)*(NBK+1));
  int*      bbase = (int*)  alloc(sizeof(int)*(NBK+1));
  int*      bfill = (int*)  alloc(sizeof(int)*(NBK));
  int*      rowptr= (int*)  alloc(sizeof(int)*(MsegP+1));                  // 1 MB
  unsigned short* srcs = (unsigned short*)alloc(sizeof(unsigned short)*((size_t)Ee+64)); // padded
  unsigned short* WTs  = (unsigned short*)alloc(sizeof(unsigned short)*(size_t)Ll*WTSL);
  float*    sel   = (float*)alloc(sizeof(float)*(size_t)Kk*256);           // 2 MB
  float*    w1e   = (float*)alloc(sizeof(float)*256*128);
  int*      inv   = (int*)  alloc(sizeof(int)*(size_t)Nn);
  int*      tflag = (int*)  alloc(sizeof(int)*NTC);
  (void)ws_size;

  k_setupA<<<MS_B+1, 256, 0, stream>>>(x, xb, inv, w1, w1e, bases, comps, roots,
                                       WTs, tflag, bcnt, hA, hB);
  k_setupB<<<(Kk+255)/256, 256, 0, stream>>>(tidx, inv, tflag);
  k_bcnt<<<NCH, 256, 0, stream>>>(ei, bcnt);
  k_bscan<<<1, 256, 0, stream>>>(bcnt, bbase, bfill, rowptr);
  k_bin<<<NCH, 256, 0, stream>>>(ei, et, bfill, ebin);
  k_sort<<<NBK, 512, 0, stream>>>(ebin, bbase, srcs, rowptr);

  const unsigned* hc = xb;
  unsigned* hn = hA;
  for (int l=0;l<Ll;l++){
    if (l < Ll-1)
      k_seg<<<MsegP/16, 256, 0, stream>>>(srcs, rowptr, hc, y2);
    else
      k_seg_t<<<(Rr*Kk+7)/8, 256, 0, stream>>>(srcs, rowptr, hc, y2, tidx);
    k_combm<<<NTC, 256, 0, stream>>>(y2, hc, WTs + (size_t)l*WTSL, biases + (size_t)l*Ff,
                                     (unsigned short*)hn, inv, sel, l, tflag);
    hc = hn;
    hn = (hn == hA) ? hB : hA;
  }
  k_mlp<<<Kk, 128, 0, stream>>>(sel, w1e, b1, w2, b2, out);
}